// Round 6
// baseline (122.378 us; speedup 1.0000x reference)
//
#include <hip/hip_runtime.h>
#include <math.h>

#define B_  8
#define S_  2048
#define H_  256
#define HK_ 128
#define P_  64
#define NQ_ 20
#define M_  (B_*S_)          // 16384 rows
// per-batch accumulator: G[20][64]@0, E[20][64]@1280, T[64]@2560, W[20]@2624, n[20]@2644, pad->2688
#define ACC_STRIDE 2688

// ws layout (float units)
#define WS_SIM   0
#define WS_CONF  16384
#define WS_ACC   32768            // 8*2688 = 21504 floats
#define WS_WT    54272            // bf16 frags: 2*8*8*64*8 = 65536 shorts = 32768 float slots

typedef __attribute__((ext_vector_type(8))) short bf16x8;
typedef __attribute__((ext_vector_type(4))) float f32x4;

// ---------------------------------------------------------------------------
// Kernel 0: prep — round w1 (fp32 [k=256][n=128]) RNE to bf16 into MFMA
// B-fragment order wtf[mlp][kt(8)][nt(8)][lane(64)][j(8)], and zero ws_acc.
// ---------------------------------------------------------------------------
__global__ void prep_kernel(const float* __restrict__ sw1, const float* __restrict__ cw1,
                            short* __restrict__ wtf, float* __restrict__ ws_acc)
{
    const int t = blockIdx.x * 256 + threadIdx.x;      // 0..8191
    const int l = t & 63, nt = (t >> 6) & 7, kt = (t >> 9) & 7, mlp = t >> 12;
    const int col = l & 15, quad = l >> 4;
    const int n = nt * 16 + col;
    const float* w1 = mlp ? cw1 : sw1;
    short frag[8];
    #pragma unroll
    for (int j = 0; j < 8; ++j) {
        int k = kt * 32 + quad * 8 + j;
        union { float f; unsigned u; } c; c.f = w1[k * HK_ + n];
        frag[j] = (short)((c.u + 0x7FFF + ((c.u >> 16) & 1)) >> 16);   // RNE
    }
    *(uint4*)(wtf + (size_t)t * 8) = *(const uint4*)frag;
    for (int s = t; s < B_ * ACC_STRIDE; s += 8192) ws_acc[s] = 0.f;
}

// ---------------------------------------------------------------------------
// Kernel 1: dual MLP via bf16 MFMA (16x16x32), 2-term A-split (Ahi+Alo).
// 32 rows/wave (two A-fragments share every B-fragment load -> halves L2
// fragment traffic vs 16 rows/wave; 4 MFMAs per b-load). No LDS, no barriers.
// 256 blocks x 4 waves; wave w: mlp=w>>1, half=w&1 -> rows bid*64+half*32+[0,32)
// Fused fp32 layer-2 epilogue: relu(h+b1)·w2 + shfl reduce -> sim / sigmoid conf.
// ---------------------------------------------------------------------------
__launch_bounds__(256)
__global__ void mlp_mfma_kernel(const float* __restrict__ fx, const short* __restrict__ wtf,
                                const float* __restrict__ sb1, const float* __restrict__ sw2,
                                const float* __restrict__ sb2, const float* __restrict__ cb1,
                                const float* __restrict__ cw2, const float* __restrict__ cb2,
                                float* __restrict__ sim, float* __restrict__ conf)
{
    const int tid  = threadIdx.x;
    const int bid  = blockIdx.x;
    const int w    = tid >> 6, l = tid & 63;
    const int col  = l & 15, quad = l >> 4;
    const int mlp  = w >> 1, half = w & 1;
    const int r0   = bid * 64 + half * 32;

    f32x4 acc0[8], acc1[8];
    #pragma unroll
    for (int nt = 0; nt < 8; ++nt) {
        acc0[nt] = (f32x4){0.f, 0.f, 0.f, 0.f};
        acc1[nt] = (f32x4){0.f, 0.f, 0.f, 0.f};
    }

    const float* fxrow0 = fx + (size_t)(r0 + col) * H_;
    const float* fxrow1 = fx + (size_t)(r0 + 16 + col) * H_;
    const short* wf = wtf + (size_t)mlp * 32768 + (size_t)l * 8;

    #pragma unroll
    for (int kt = 0; kt < 8; ++kt) {
        bf16x8 ahi[2], alo[2];
        #pragma unroll
        for (int rt = 0; rt < 2; ++rt) {
            const float* fr = rt ? fxrow1 : fxrow0;
            float4 a0 = *(const float4*)(fr + kt * 32 + quad * 8);
            float4 a1 = *(const float4*)(fr + kt * 32 + quad * 8 + 4);
            float af[8] = {a0.x, a0.y, a0.z, a0.w, a1.x, a1.y, a1.z, a1.w};
            #pragma unroll
            for (int i = 0; i < 8; ++i) {
                union { float f; unsigned u; } c; c.f = af[i];
                unsigned hi = c.u >> 16;                   // truncate: lo holds residual
                ahi[rt][i] = (short)hi;
                union { float f; unsigned u; } h2; h2.u = hi << 16;
                union { float f; unsigned u; } c2; c2.f = af[i] - h2.f;
                alo[rt][i] = (short)(c2.u >> 16);
            }
        }
        const short* base = wf + (size_t)kt * 4096;
        #pragma unroll
        for (int nt = 0; nt < 8; ++nt) {
            bf16x8 bf = *(const bf16x8*)(base + nt * 512);
            acc0[nt] = __builtin_amdgcn_mfma_f32_16x16x32_bf16(ahi[0], bf, acc0[nt], 0, 0, 0);
            acc0[nt] = __builtin_amdgcn_mfma_f32_16x16x32_bf16(alo[0], bf, acc0[nt], 0, 0, 0);
            acc1[nt] = __builtin_amdgcn_mfma_f32_16x16x32_bf16(ahi[1], bf, acc1[nt], 0, 0, 0);
            acc1[nt] = __builtin_amdgcn_mfma_f32_16x16x32_bf16(alo[1], bf, acc1[nt], 0, 0, 0);
        }
    }

    // fp32 layer-2 epilogue (both row-tiles)
    const float* b1 = mlp ? cb1 : sb1;
    const float* w2 = mlp ? cw2 : sw2;
    const float  b2v = mlp ? cb2[0] : sb2[0];
    float p0[4] = {0.f, 0.f, 0.f, 0.f};
    float p1[4] = {0.f, 0.f, 0.f, 0.f};
    #pragma unroll
    for (int nt = 0; nt < 8; ++nt) {
        float b1c = b1[nt * 16 + col];
        float w2c = w2[nt * 16 + col];
        #pragma unroll
        for (int j = 0; j < 4; ++j) {
            p0[j] += fmaxf(acc0[nt][j] + b1c, 0.f) * w2c;
            p1[j] += fmaxf(acc1[nt][j] + b1c, 0.f) * w2c;
        }
    }
    #pragma unroll
    for (int off = 8; off >= 1; off >>= 1)
        #pragma unroll
        for (int j = 0; j < 4; ++j) {
            p0[j] += __shfl_down(p0[j], off, 16);
            p1[j] += __shfl_down(p1[j], off, 16);
        }

    if (col == 0) {
        #pragma unroll
        for (int j = 0; j < 4; ++j) {
            int ra = r0 + quad * 4 + j;          // D row = quad*4+reg
            int rb = ra + 16;
            float va = p0[j] + b2v;
            float vb = p1[j] + b2v;
            if (mlp == 0) { sim[ra] = va; sim[rb] = vb; }
            else { conf[ra] = 1.0f / (1.0f + expf(-va));
                   conf[rb] = 1.0f / (1.0f + expf(-vb)); }
        }
    }
}

// ---------------------------------------------------------------------------
// Kernel 2: bucketed sums over param_x + denominator stats.
// 64 blocks: batch b = bid>>3, 256-row chunk = bid&7. Private per-wave LDS
// arrays (no LDS atomics), 4x fewer global atomics than 256-block version.
// ---------------------------------------------------------------------------
__launch_bounds__(256)
__global__ void accum_kernel(const float* __restrict__ sim, const int* __restrict__ questions,
                             const float* __restrict__ px, float* __restrict__ ws_acc)
{
    const int b = blockIdx.x >> 3;
    const int chunk = blockIdx.x & 7;     // 8 chunks of 256 rows
    const int tid = threadIdx.x;
    const int lane = tid & 63;            // p index
    const int g = tid >> 6;               // wave 0..3
    __shared__ float accs[4][ACC_STRIDE];
    for (int s = tid; s < 4 * ACC_STRIDE; s += 256) ((float*)accs)[s] = 0.f;
    __syncthreads();

    const float* simb = sim + b * S_;
    const int*   qb   = questions + b * S_;
    const float* pxb  = px + (size_t)b * S_ * P_;

    float Treg = 0.f;
    const int i0 = chunk * 256 + g;
    for (int t = 0; t < 64; ++t) {
        int i = i0 + 4 * t;
        int qi = qb[i];                       // wave-uniform -> broadcast
        float e = expf(simb[i]);
        float v = pxb[(size_t)i * P_ + lane]; // coalesced 256B per wave
        Treg += v;
        accs[g][qi * 64 + lane]        += v;       // G_q
        accs[g][(20 + qi) * 64 + lane] += e * v;   // E_q
        if (lane == 0) {
            accs[g][2624 + qi] += e;               // W_q (denominator exp-sum)
            accs[g][2644 + qi] += 1.0f;            // n_q (group size)
        }
    }
    accs[g][2560 + lane] += Treg;                  // T
    __syncthreads();

    float* dst = ws_acc + (size_t)b * ACC_STRIDE;
    for (int s = tid; s < ACC_STRIDE; s += 256) {
        float sum = accs[0][s] + accs[1][s] + accs[2][s] + accs[3][s];
        atomicAdd(dst + s, sum);
    }
}

// ---------------------------------------------------------------------------
// Kernel 3: out = c*px + (1-c) * ((T - G_q + E_q) / ((S-n_q)+W_q)), float4/thread
// ---------------------------------------------------------------------------
__global__ void output_kernel(const float* __restrict__ px, const float* __restrict__ conf,
                              const int* __restrict__ questions, const float* __restrict__ ws_acc,
                              float* __restrict__ out)
{
    const int idx = blockIdx.x * 256 + threadIdx.x;  // float4 units, 262144 total
    const int row = idx >> 4;                        // b*S + s
    const int p4  = idx & 15;
    const int b   = row >> 11;                       // S = 2048
    const float c = conf[row];
    const int   q = questions[row];
    const float* accb = ws_acc + (size_t)b * ACC_STRIDE;
    const float4 T = *(const float4*)(accb + 2560 + p4 * 4);
    const float4 G = *(const float4*)(accb + q * 64 + p4 * 4);
    const float4 E = *(const float4*)(accb + (20 + q) * 64 + p4 * 4);
    const float denom = ((float)S_ - accb[2644 + q]) + accb[2624 + q];
    const float inv = 1.0f / denom;
    const float4 pv = ((const float4*)px)[idx];
    const float om = 1.0f - c;
    float4 o;
    o.x = c * pv.x + om * ((T.x - G.x + E.x) * inv);
    o.y = c * pv.y + om * ((T.y - G.y + E.y) * inv);
    o.z = c * pv.z + om * ((T.z - G.z + E.z) * inv);
    o.w = c * pv.w + om * ((T.w - G.w + E.w) * inv);
    ((float4*)out)[idx] = o;
}

// ---------------------------------------------------------------------------
extern "C" void kernel_launch(void* const* d_in, const int* in_sizes, int n_in,
                              void* d_out, int out_size, void* d_ws, size_t ws_size,
                              hipStream_t stream) {
    const float* fx  = (const float*)d_in[0];
    const float* px  = (const float*)d_in[1];
    const float* sw1 = (const float*)d_in[2];
    const float* sb1 = (const float*)d_in[3];
    const float* sw2 = (const float*)d_in[4];
    const float* sb2 = (const float*)d_in[5];
    const float* cw1 = (const float*)d_in[6];
    const float* cb1 = (const float*)d_in[7];
    const float* cw2 = (const float*)d_in[8];
    const float* cb2 = (const float*)d_in[9];
    const int* questions = (const int*)d_in[10];
    float* out = (float*)d_out;

    float* ws     = (float*)d_ws;
    float* sim    = ws + WS_SIM;
    float* conf   = ws + WS_CONF;
    float* ws_acc = ws + WS_ACC;
    short* wtf    = (short*)(ws + WS_WT);

    prep_kernel<<<32, 256, 0, stream>>>(sw1, cw1, wtf, ws_acc);
    mlp_mfma_kernel<<<M_ / 64, 256, 0, stream>>>(fx, wtf, sb1, sw2, sb2,
                                                 cb1, cw2, cb2, sim, conf);
    accum_kernel<<<B_ * 8, 256, 0, stream>>>(sim, questions, px, ws_acc);
    output_kernel<<<(M_ * P_ / 4) / 256, 256, 0, stream>>>(px, conf, questions,
                                                           ws_acc, out);
}

// Round 7
// 110.475 us; speedup vs baseline: 1.1077x; 1.1077x over previous
//
#include <hip/hip_runtime.h>
#include <math.h>

#define B_  8
#define S_  2048
#define H_  256
#define HK_ 128
#define P_  64
#define NQ_ 20
#define M_  (B_*S_)          // 16384 rows
// per-batch accumulator: G[20][64]@0, E[20][64]@1280, T[64]@2560, W[20]@2624, n[20]@2644, pad->2688
#define ACC_STRIDE 2688

// ws layout (float units)
#define WS_SIM   0
#define WS_CONF  16384
#define WS_ACC   32768            // 8*2688 = 21504 floats
#define WS_WT    54272            // bf16 frags: 2*8*8*64*8 = 65536 shorts = 32768 float slots

typedef __attribute__((ext_vector_type(8))) short bf16x8;
typedef __attribute__((ext_vector_type(4))) float f32x4;

// ---------------------------------------------------------------------------
// Kernel 0: prep — round w1 (fp32 [k=256][n=128]) RNE to bf16 and scatter into
// MFMA B-fragment order wtf[mlp][kt(8)][nt(8)][lane(64)][j(8)]:
//   lane l -> col=l&15, quad=l>>4;  element j: B[k = kt*32+quad*8+j][n = nt*16+col]
// Also zeros the ws accumulator region. 8192 threads, each writes one 16B frag.
// ---------------------------------------------------------------------------
__global__ void prep_kernel(const float* __restrict__ sw1, const float* __restrict__ cw1,
                            short* __restrict__ wtf, float* __restrict__ ws_acc)
{
    const int t = blockIdx.x * 256 + threadIdx.x;      // 0..8191
    const int l = t & 63, nt = (t >> 6) & 7, kt = (t >> 9) & 7, mlp = t >> 12;
    const int col = l & 15, quad = l >> 4;
    const int n = nt * 16 + col;
    const float* w1 = mlp ? cw1 : sw1;
    short frag[8];
    #pragma unroll
    for (int j = 0; j < 8; ++j) {
        int k = kt * 32 + quad * 8 + j;
        union { float f; unsigned u; } c; c.f = w1[k * HK_ + n];
        frag[j] = (short)((c.u + 0x7FFF + ((c.u >> 16) & 1)) >> 16);   // RNE
    }
    *(uint4*)(wtf + (size_t)t * 8) = *(const uint4*)frag;
    for (int s = t; s < B_ * ACC_STRIDE; s += 8192) ws_acc[s] = 0.f;
}

// ---------------------------------------------------------------------------
// Kernel 1: dual MLP via bf16 MFMA (16x16x32), 2-term A-split (Ahi+Alo).
// NO LDS, no barriers: B-fragments loaded straight from global (L2-broadcast,
// fragment-ordered so each load is a fully coalesced 1KB wave read).
// Block = 4 waves; wave w: mlp=w>>1, row-tile mt=w&1 (32 rows/block).
// 512 blocks — max occupancy; R6 showed 64-rows/wave (2x VGPR, half blocks)
// regresses 13 us: this kernel is latency-bound, parallelism wins.
// Fused fp32 layer-2 epilogue: relu(h+b1)·w2 + shfl reduce -> sim / sigmoid conf.
// ---------------------------------------------------------------------------
__launch_bounds__(256)
__global__ void mlp_mfma_kernel(const float* __restrict__ fx, const short* __restrict__ wtf,
                                const float* __restrict__ sb1, const float* __restrict__ sw2,
                                const float* __restrict__ sb2, const float* __restrict__ cb1,
                                const float* __restrict__ cw2, const float* __restrict__ cb2,
                                float* __restrict__ sim, float* __restrict__ conf)
{
    const int tid  = threadIdx.x;
    const int w    = tid >> 6, l = tid & 63;
    const int col  = l & 15, quad = l >> 4;
    const int mlp  = w >> 1, mt = w & 1;
    const int row  = blockIdx.x * 32 + mt * 16 + col;  // A-operand m = lane&15

    f32x4 acc[8];
    #pragma unroll
    for (int nt = 0; nt < 8; ++nt) acc[nt] = (f32x4){0.f, 0.f, 0.f, 0.f};

    const float* fxrow = fx + (size_t)row * H_;
    const short* wf = wtf + (size_t)mlp * 32768 + (size_t)l * 8;

    #pragma unroll
    for (int kt = 0; kt < 8; ++kt) {
        float4 a0 = *(const float4*)(fxrow + kt * 32 + quad * 8);
        float4 a1 = *(const float4*)(fxrow + kt * 32 + quad * 8 + 4);
        float af[8] = {a0.x, a0.y, a0.z, a0.w, a1.x, a1.y, a1.z, a1.w};
        bf16x8 ahi, alo;
        #pragma unroll
        for (int i = 0; i < 8; ++i) {
            union { float f; unsigned u; } c; c.f = af[i];
            unsigned hi = c.u >> 16;                       // truncate: lo holds residual
            ahi[i] = (short)hi;
            union { float f; unsigned u; } h2; h2.u = hi << 16;
            union { float f; unsigned u; } c2; c2.f = af[i] - h2.f;
            alo[i] = (short)(c2.u >> 16);
        }
        const short* base = wf + (size_t)kt * 4096;
        #pragma unroll
        for (int nt = 0; nt < 8; ++nt) {
            bf16x8 bf = *(const bf16x8*)(base + nt * 512);
            acc[nt] = __builtin_amdgcn_mfma_f32_16x16x32_bf16(ahi, bf, acc[nt], 0, 0, 0);
            acc[nt] = __builtin_amdgcn_mfma_f32_16x16x32_bf16(alo, bf, acc[nt], 0, 0, 0);
        }
    }

    // fp32 layer-2 epilogue
    const float* b1 = mlp ? cb1 : sb1;
    const float* w2 = mlp ? cw2 : sw2;
    const float  b2v = mlp ? cb2[0] : sb2[0];
    float p[4] = {0.f, 0.f, 0.f, 0.f};
    #pragma unroll
    for (int nt = 0; nt < 8; ++nt) {
        float b1c = b1[nt * 16 + col];
        float w2c = w2[nt * 16 + col];
        #pragma unroll
        for (int j = 0; j < 4; ++j)
            p[j] += fmaxf(acc[nt][j] + b1c, 0.f) * w2c;
    }
    #pragma unroll
    for (int off = 8; off >= 1; off >>= 1)
        #pragma unroll
        for (int j = 0; j < 4; ++j) p[j] += __shfl_down(p[j], off, 16);

    if (col == 0) {
        #pragma unroll
        for (int j = 0; j < 4; ++j) {
            int r = blockIdx.x * 32 + mt * 16 + quad * 4 + j;   // D row = quad*4+reg
            float v = p[j] + b2v;
            if (mlp == 0) sim[r] = v;
            else          conf[r] = 1.0f / (1.0f + expf(-v));
        }
    }
}

// ---------------------------------------------------------------------------
// Kernel 2: bucketed sums over param_x + softmax-denominator stats.
// Per block: batch b, 64-row chunk (256 blocks — keep parallelism; R6's
// 64-block variant regressed). LDS accumulators, atomicAdd flush.
// ---------------------------------------------------------------------------
__launch_bounds__(256)
__global__ void accum_kernel(const float* __restrict__ sim, const int* __restrict__ questions,
                             const float* __restrict__ px, float* __restrict__ ws_acc)
{
    const int b = blockIdx.x;
    const int chunk = blockIdx.y;         // 32 chunks of 64 rows
    const int tid = threadIdx.x;
    const int lane = tid & 63;            // p index
    const int g = tid >> 6;               // group 0..3
    __shared__ float accs[4][ACC_STRIDE];
    for (int s = tid; s < 4 * ACC_STRIDE; s += 256) ((float*)accs)[s] = 0.f;
    __syncthreads();

    const float* simb = sim + b * S_;
    const int*   qb   = questions + b * S_;
    const float* pxb  = px + (size_t)b * S_ * P_;

    float Treg = 0.f;
    const int i0 = chunk * 64 + g;
    for (int t = 0; t < 16; ++t) {
        int i = i0 + 4 * t;
        int qi = qb[i];                       // uniform across group -> broadcast
        float e = expf(simb[i]);
        float v = pxb[(size_t)i * P_ + lane]; // coalesced 256B per group
        Treg += v;
        accs[g][qi * 64 + lane]        += v;       // G_q
        accs[g][(20 + qi) * 64 + lane] += e * v;   // E_q
        if (lane == 0) {
            accs[g][2624 + qi] += e;               // W_q (denominator exp-sum)
            accs[g][2644 + qi] += 1.0f;            // n_q (group size)
        }
    }
    accs[g][2560 + lane] += Treg;                  // T
    __syncthreads();

    float* dst = ws_acc + (size_t)b * ACC_STRIDE;
    for (int s = tid; s < ACC_STRIDE; s += 256) {
        float sum = accs[0][s] + accs[1][s] + accs[2][s] + accs[3][s];
        atomicAdd(dst + s, sum);
    }
}

// ---------------------------------------------------------------------------
// Kernel 3: out = c*px + (1-c) * ((T - G_q + E_q) / ((S-n_q)+W_q)), float4/thread
// ---------------------------------------------------------------------------
__global__ void output_kernel(const float* __restrict__ px, const float* __restrict__ conf,
                              const int* __restrict__ questions, const float* __restrict__ ws_acc,
                              float* __restrict__ out)
{
    const int idx = blockIdx.x * 256 + threadIdx.x;  // float4 units, 262144 total
    const int row = idx >> 4;                        // b*S + s
    const int p4  = idx & 15;
    const int b   = row >> 11;                       // S = 2048
    const float c = conf[row];
    const int   q = questions[row];
    const float* accb = ws_acc + (size_t)b * ACC_STRIDE;
    const float4 T = *(const float4*)(accb + 2560 + p4 * 4);
    const float4 G = *(const float4*)(accb + q * 64 + p4 * 4);
    const float4 E = *(const float4*)(accb + (20 + q) * 64 + p4 * 4);
    const float denom = ((float)S_ - accb[2644 + q]) + accb[2624 + q];
    const float inv = 1.0f / denom;
    const float4 pv = ((const float4*)px)[idx];
    const float om = 1.0f - c;
    float4 o;
    o.x = c * pv.x + om * ((T.x - G.x + E.x) * inv);
    o.y = c * pv.y + om * ((T.y - G.y + E.y) * inv);
    o.z = c * pv.z + om * ((T.z - G.z + E.z) * inv);
    o.w = c * pv.w + om * ((T.w - G.w + E.w) * inv);
    ((float4*)out)[idx] = o;
}

// ---------------------------------------------------------------------------
extern "C" void kernel_launch(void* const* d_in, const int* in_sizes, int n_in,
                              void* d_out, int out_size, void* d_ws, size_t ws_size,
                              hipStream_t stream) {
    const float* fx  = (const float*)d_in[0];
    const float* px  = (const float*)d_in[1];
    const float* sw1 = (const float*)d_in[2];
    const float* sb1 = (const float*)d_in[3];
    const float* sw2 = (const float*)d_in[4];
    const float* sb2 = (const float*)d_in[5];
    const float* cw1 = (const float*)d_in[6];
    const float* cb1 = (const float*)d_in[7];
    const float* cw2 = (const float*)d_in[8];
    const float* cb2 = (const float*)d_in[9];
    const int* questions = (const int*)d_in[10];
    float* out = (float*)d_out;

    float* ws     = (float*)d_ws;
    float* sim    = ws + WS_SIM;
    float* conf   = ws + WS_CONF;
    float* ws_acc = ws + WS_ACC;
    short* wtf    = (short*)(ws + WS_WT);

    prep_kernel<<<32, 256, 0, stream>>>(sw1, cw1, wtf, ws_acc);
    mlp_mfma_kernel<<<M_ / 32, 256, 0, stream>>>(fx, wtf, sb1, sw2, sb2,
                                                 cb1, cw2, cb2, sim, conf);
    accum_kernel<<<dim3(B_, 32), 256, 0, stream>>>(sim, questions, px, ws_acc);
    output_kernel<<<(M_ * P_ / 4) / 256, 256, 0, stream>>>(px, conf, questions,
                                                           ws_acc, out);
}